// Round 8
// baseline (210.115 us; speedup 1.0000x reference)
//
#include <hip/hip_runtime.h>
#include <hip/hip_bf16.h>

#define HIDDEN 512
#define M_PER_TOKEN 32
#define BUCKET_CAP 32   // Poisson(5.24) users/row; P(>32) ~ 1e-11 for 50k rows

typedef _Float16 half8 __attribute__((ext_vector_type(8)));
typedef float    f32x4 __attribute__((ext_vector_type(4)));

// ---------------------------------------------------------------------------
// K1 (fused): blocks [0, conv_blocks) convert input fp32 -> fp16 table;
// blocks [conv_blocks, ...) scatter the inverted index (4 pairs/thread).
// Both halves are independent: counts is pre-zeroed by hipMemsetAsync, and
// padded needs NO zero-init (row_ffn bounds-sanitizes speculative pids).
// ---------------------------------------------------------------------------
__global__ __launch_bounds__(256) void prep_scatter_kernel(
    const float* __restrict__ input,   // [8192*512]
    _Float16*    __restrict__ in_h,    // [8192*512]
    const int*   __restrict__ mask,    // [262144]
    int*         __restrict__ counts,  // [n_rows] (pre-zeroed)
    int*         __restrict__ padded,  // [n_rows*32] (uninitialized ok)
    int n_chunks, int n_pairs, int conv_blocks)
{
    const int bid = blockIdx.x;
    if (bid < conv_blocks) {
        int i = bid * 256 + threadIdx.x;
        if (i < n_chunks) {
            const float4 a = ((const float4*)input)[2 * i];
            const float4 b = ((const float4*)input)[2 * i + 1];
            half8 h;
            h[0] = (_Float16)a.x; h[1] = (_Float16)a.y;
            h[2] = (_Float16)a.z; h[3] = (_Float16)a.w;
            h[4] = (_Float16)b.x; h[5] = (_Float16)b.y;
            h[6] = (_Float16)b.z; h[7] = (_Float16)b.w;
            ((half8*)in_h)[i] = h;
        }
    } else {
        int t    = (bid - conv_blocks) * 256 + threadIdx.x;
        int base = t * 4;
        if (base + 3 < n_pairs) {
            const int4 m = *(const int4*)(mask + base);
            int r, slot;
            r = m.x; slot = atomicAdd(&counts[r], 1);
            if (slot < BUCKET_CAP) padded[(r << 5) + slot] = base;
            r = m.y; slot = atomicAdd(&counts[r], 1);
            if (slot < BUCKET_CAP) padded[(r << 5) + slot] = base + 1;
            r = m.z; slot = atomicAdd(&counts[r], 1);
            if (slot < BUCKET_CAP) padded[(r << 5) + slot] = base + 2;
            r = m.w; slot = atomicAdd(&counts[r], 1);
            if (slot < BUCKET_CAP) padded[(r << 5) + slot] = base + 3;
        } else {
            for (int i = base; i < n_pairs; ++i) {
                int r = mask[i];
                int slot = atomicAdd(&counts[r], 1);
                if (slot < BUCKET_CAP) padded[(r << 5) + slot] = i;
            }
        }
    }
}

// ---------------------------------------------------------------------------
// 16-lane sum via DPP butterfly (verified rounds 4-6): quad_perm XOR1, XOR2,
// row_half_mirror, row_mirror -> all 16 sublanes end with the total.
// ---------------------------------------------------------------------------
template <int CTRL>
__device__ __forceinline__ float dpp_add(float v) {
    return v + __int_as_float(__builtin_amdgcn_update_dpp(
        0, __float_as_int(v), CTRL, 0xF, 0xF, true));
}

__device__ __forceinline__ float red16(float v) {
    v = dpp_add<0xB1>(v);   // quad_perm [1,0,3,2]  : i ^ 1
    v = dpp_add<0x4E>(v);   // quad_perm [2,3,0,1]  : i ^ 2
    v = dpp_add<0x141>(v);  // row_half_mirror      : i <-> 7-i within 8
    v = dpp_add<0x140>(v);  // row_mirror           : i <-> 15-i within 16
    return v;
}

__device__ __forceinline__ float dot128(const half8 h, const f32x4 wa,
                                        const f32x4 wb) {
    return (float)h[0]*wa[0] + (float)h[1]*wa[1]
         + (float)h[2]*wa[2] + (float)h[3]*wa[3]
         + (float)h[4]*wb[0] + (float)h[5]*wb[1]
         + (float)h[6]*wb[2] + (float)h[7]*wb[3];
}

// ---------------------------------------------------------------------------
// K3 v10: 4 DISTINCT rows per wave (quarter q <-> row base+q, 16 lanes/row).
//  - v6-v9 post-mortem: all pipelining variants landed at ~2.5 TB/s because
//    quarters duplicated weight addresses and gathers -> only ~2 KB distinct
//    bytes in flight per wave. v10 makes every lane carry unique data:
//    weight prologue 8 KB distinct/wave, gathers 4 KB distinct/iteration,
//    same instruction count. 4x the memory-level parallelism per wave.
//  - users iterate serially per quarter under exec-mask (no wasted gathers
//    on count imbalance); one-ahead pid prefetch, bounds-sanitized (padded
//    is NOT zero-initialized).
//  - low VGPR (~64) -> 8 waves/SIMD for TLP-based latency hiding.
// ---------------------------------------------------------------------------
__global__ __launch_bounds__(256) void row_ffn_kernel(
    const _Float16* __restrict__ in_h,    // [8192, 512] fp16
    const float*    __restrict__ weight,  // [n_rows, 512] fp32
    const float*    __restrict__ bias,    // [n_rows]
    const int*      __restrict__ counts,  // [n_rows]
    const int*      __restrict__ padded,  // [n_rows, 32]
    float*          __restrict__ out,     // [8192, 32]
    int n_rows, int n_pairs, int blocks_per_xcd)
{
    const int b    = (int)blockIdx.x;
    const int bsw  = (b & 7) * blocks_per_xcd + (b >> 3);  // XCD-contiguous
    const int wave = threadIdx.x >> 6;
    const int lane = threadIdx.x & 63;
    const int s    = lane & 15;   // sublane within quarter (element chunk)
    const int q    = lane >> 4;   // quarter = which ROW of the group of 4

    const int r = bsw * 16 + wave * 4 + q;     // this lane's row
    if (bsw * 16 >= n_rows) return;
    const int rc = (r < n_rows) ? r : n_rows - 1;   // clamped for safe loads

    const int* users = padded + ((size_t)rc << 5);

    // front-loaded independent issues: count, speculative pid0, bias, weight
    const int   c_raw = counts[rc];
    int         pid   = users[0];              // may be poison if c==0
    const float bv    = bias[rc];

    const float* wbase = weight + (size_t)rc * HIDDEN + s * 8;
    const f32x4 w0 = __builtin_nontemporal_load((const f32x4*)(wbase +   0));
    const f32x4 w1 = __builtin_nontemporal_load((const f32x4*)(wbase +   4));
    const f32x4 w2 = __builtin_nontemporal_load((const f32x4*)(wbase + 128));
    const f32x4 w3 = __builtin_nontemporal_load((const f32x4*)(wbase + 132));
    const f32x4 w4 = __builtin_nontemporal_load((const f32x4*)(wbase + 256));
    const f32x4 w5 = __builtin_nontemporal_load((const f32x4*)(wbase + 260));
    const f32x4 w6 = __builtin_nontemporal_load((const f32x4*)(wbase + 384));
    const f32x4 w7 = __builtin_nontemporal_load((const f32x4*)(wbase + 388));

    int c = (r < n_rows) ? ((c_raw > BUCKET_CAP) ? BUCKET_CAP : c_raw) : 0;
    if ((unsigned)pid >= (unsigned)n_pairs) pid = 0;   // sanitize speculation

    for (int i = 0; ; ++i) {
        const bool act = i < c;
        if (__ballot(act) == 0ull) break;      // whole wave done

        int pidn = users[(i + 1) & 31];        // prefetch next slot
        if ((unsigned)pidn >= (unsigned)n_pairs) pidn = 0;

        if (act) {                             // quarter-uniform exec mask
            const _Float16* ir = in_h + (size_t)(pid >> 5) * HIDDEN + s * 8;
            const half8 h0 = *(const half8*)(ir);
            const half8 h1 = *(const half8*)(ir + 128);
            const half8 h2 = *(const half8*)(ir + 256);
            const half8 h3 = *(const half8*)(ir + 384);

            float d = dot128(h0, w0, w1) + dot128(h1, w2, w3)
                    + dot128(h2, w4, w5) + dot128(h3, w6, w7);
            d = red16(d);
            if (s == 0) {
                float v = d + bv;
                out[pid] = v > 0.0f ? v : 0.0f;
            }
        }
        pid = pidn;
    }
}

// ---------------------------------------------------------------------------
// Fallback (ws too small): round-1 fp32 token-centric, known-good 97us.
// ---------------------------------------------------------------------------
__global__ __launch_bounds__(256) void dynamic_ffn_f32_kernel(
    const float* __restrict__ input,
    const int*   __restrict__ mask,
    const float* __restrict__ weight,
    const float* __restrict__ bias,
    float*       __restrict__ out,
    int n_tokens)
{
    const int token = blockIdx.x;
    if (token >= n_tokens) return;
    const int wave = threadIdx.x >> 6;
    const int lane = threadIdx.x & 63;

    const float* in_row = input + (size_t)token * HIDDEN + lane * 8;
    const float4 x0 = *(const float4*)(in_row);
    const float4 x1 = *(const float4*)(in_row + 4);

    const int* midx = mask + (size_t)token * M_PER_TOKEN + wave * 8;
    float*     orow = out  + (size_t)token * M_PER_TOKEN + wave * 8;

    int idx[8];
#pragma unroll
    for (int j = 0; j < 8; ++j) idx[j] = midx[j];

    float acc[8];
#pragma unroll
    for (int j = 0; j < 8; ++j) {
        const float* w = weight + (size_t)idx[j] * HIDDEN + lane * 8;
        const float4 a = *(const float4*)(w);
        const float4 b = *(const float4*)(w + 4);
        acc[j] = x0.x * a.x + x0.y * a.y + x0.z * a.z + x0.w * a.w
               + x1.x * b.x + x1.y * b.y + x1.z * b.z + x1.w * b.w;
    }
#pragma unroll
    for (int j = 0; j < 8; ++j) {
        float p = acc[j];
#pragma unroll
        for (int off = 32; off > 0; off >>= 1)
            p += __shfl_down(p, off, 64);
        if (lane == 0) {
            float v = p + bias[idx[j]];
            orow[j] = v > 0.0f ? v : 0.0f;
        }
    }
}

extern "C" void kernel_launch(void* const* d_in, const int* in_sizes, int n_in,
                              void* d_out, int out_size, void* d_ws, size_t ws_size,
                              hipStream_t stream) {
    const float* input  = (const float*)d_in[0];   // [4,2048,512] fp32
    const int*   mask   = (const int*)  d_in[1];   // [4,2048,32] int32
    const float* weight = (const float*)d_in[2];   // [50000,512] fp32
    const float* bias   = (const float*)d_in[3];   // [50000] fp32
    float*       out    = (float*)d_out;           // [4,2048,32] fp32

    const int n_tokens = in_sizes[0] / HIDDEN;     // 8192
    const int n_pairs  = in_sizes[1];              // 262144
    const int n_rows   = in_sizes[2] / HIDDEN;     // 50000

    const size_t in_h_bytes   = (size_t)in_sizes[0] * sizeof(_Float16);    // 8.4MB
    const size_t counts_bytes = (size_t)n_rows * sizeof(int);              // 200KB
    const size_t padded_bytes = (size_t)n_rows * BUCKET_CAP * sizeof(int); // 6.4MB
    const size_t need = in_h_bytes + counts_bytes + padded_bytes;

    if (ws_size >= need) {
        _Float16* in_h   = (_Float16*)d_ws;
        int*      counts = (int*)((char*)d_ws + in_h_bytes);
        int*      padded = (int*)((char*)d_ws + in_h_bytes + counts_bytes);

        hipMemsetAsync(counts, 0, counts_bytes, stream);

        const int n_chunks    = in_sizes[0] / 8;               // 524288
        const int conv_blocks = (n_chunks + 255) / 256;        // 2048
        const int sc_threads  = (n_pairs + 3) / 4;             // 65536
        const int sc_blocks   = (sc_threads + 255) / 256;      // 256
        prep_scatter_kernel<<<conv_blocks + sc_blocks, 256, 0, stream>>>(
            input, in_h, mask, counts, padded, n_chunks, n_pairs, conv_blocks);

        const int n_blocks       = (n_rows + 15) / 16;         // 3125
        const int blocks_per_xcd = (n_blocks + 7) / 8;         // 391
        const int grid           = blocks_per_xcd * 8;         // 3128
        row_ffn_kernel<<<grid, 256, 0, stream>>>(
            in_h, weight, bias, counts, padded, out,
            n_rows, n_pairs, blocks_per_xcd);
    } else {
        dynamic_ffn_f32_kernel<<<n_tokens, 256, 0, stream>>>(
            input, mask, weight, bias, out, n_tokens);
    }
}

// Round 9
// 201.172 us; speedup vs baseline: 1.0445x; 1.0445x over previous
//
#include <hip/hip_runtime.h>
#include <hip/hip_bf16.h>

#define HIDDEN 512
#define M_PER_TOKEN 32
#define BUCKET_CAP 32   // Poisson(5.24) users/row; P(>32) ~ 1e-11 for 50k rows

typedef _Float16 half8 __attribute__((ext_vector_type(8)));
typedef float    f32x4 __attribute__((ext_vector_type(4)));

// ---------------------------------------------------------------------------
// K1: input fp32 -> fp16 (8.4 MB gathered-side table) + zero counts + zero
// slots 0..3 of every bucket (so row_ffn can speculatively read users[q]
// before counts arrives).
// ---------------------------------------------------------------------------
__global__ __launch_bounds__(256) void prep_kernel(
    const float* __restrict__ input,   // [8192*512]
    _Float16*    __restrict__ in_h,    // [8192*512]
    int*         __restrict__ counts,  // [n_rows]
    int*         __restrict__ padded,  // [n_rows*32]
    int n_chunks, int n_rows)
{
    int i = blockIdx.x * 256 + threadIdx.x;
    if (i < n_chunks) {
        const float4 a = ((const float4*)input)[2 * i];
        const float4 b = ((const float4*)input)[2 * i + 1];
        half8 h;
        h[0] = (_Float16)a.x; h[1] = (_Float16)a.y;
        h[2] = (_Float16)a.z; h[3] = (_Float16)a.w;
        h[4] = (_Float16)b.x; h[5] = (_Float16)b.y;
        h[6] = (_Float16)b.z; h[7] = (_Float16)b.w;
        ((half8*)in_h)[i] = h;
    }
    if (i < n_rows) {
        counts[i] = 0;
        *(int4*)(padded + ((size_t)i << 5)) = make_int4(0, 0, 0, 0);
    }
}

// ---------------------------------------------------------------------------
// K2: inverted index. 4 pairs per thread (int4 mask load); bucket slot via
// atomicAdd. 262144 pairs -> 65536 threads.
// ---------------------------------------------------------------------------
__global__ __launch_bounds__(256) void scatter_kernel(
    const int* __restrict__ mask,     // [262144]
    int*       __restrict__ counts,   // [n_rows]
    int*       __restrict__ padded,   // [n_rows*32]
    int n_pairs)
{
    int t    = blockIdx.x * 256 + threadIdx.x;
    int base = t * 4;
    if (base + 3 < n_pairs) {
        const int4 m = *(const int4*)(mask + base);
        int r, slot;
        r = m.x; slot = atomicAdd(&counts[r], 1);
        if (slot < BUCKET_CAP) padded[(r << 5) + slot] = base;
        r = m.y; slot = atomicAdd(&counts[r], 1);
        if (slot < BUCKET_CAP) padded[(r << 5) + slot] = base + 1;
        r = m.z; slot = atomicAdd(&counts[r], 1);
        if (slot < BUCKET_CAP) padded[(r << 5) + slot] = base + 2;
        r = m.w; slot = atomicAdd(&counts[r], 1);
        if (slot < BUCKET_CAP) padded[(r << 5) + slot] = base + 3;
    } else {
        for (int i = base; i < n_pairs; ++i) {
            int r = mask[i];
            int slot = atomicAdd(&counts[r], 1);
            if (slot < BUCKET_CAP) padded[(r << 5) + slot] = i;
        }
    }
}

// ---------------------------------------------------------------------------
// 16-lane sum via DPP butterfly: quad_perm XOR1, XOR2, row_half_mirror,
// row_mirror. Symmetric permutations -> all 16 sublanes end with the total.
// dpp_ctrl must be an ICE at the builtin call -> template parameter.
// ---------------------------------------------------------------------------
template <int CTRL>
__device__ __forceinline__ float dpp_add(float v) {
    return v + __int_as_float(__builtin_amdgcn_update_dpp(
        0, __float_as_int(v), CTRL, 0xF, 0xF, true));
}

__device__ __forceinline__ float red16(float v) {
    v = dpp_add<0xB1>(v);   // quad_perm [1,0,3,2]  : i ^ 1
    v = dpp_add<0x4E>(v);   // quad_perm [2,3,0,1]  : i ^ 2
    v = dpp_add<0x141>(v);  // row_half_mirror      : i <-> 7-i within 8
    v = dpp_add<0x140>(v);  // row_mirror           : i <-> 15-i within 16
    return v;               // all 16 lanes hold the total
}

__device__ __forceinline__ float dot128(const half8 h, const f32x4 wa,
                                        const f32x4 wb) {
    return (float)h[0]*wa[0] + (float)h[1]*wa[1]
         + (float)h[2]*wa[2] + (float)h[3]*wa[3]
         + (float)h[4]*wb[0] + (float)h[5]*wb[1]
         + (float)h[6]*wb[2] + (float)h[7]*wb[3];
}

// ---------------------------------------------------------------------------
// K3 v8 (best measured: 201.2 us total): row-centric quarter-wave users +
// 2-stage gather pipeline. Final form — six structural variants (v6-v10)
// all converge to ~60 us for this kernel because it sits at the traffic
// floor: ~370 MB/iteration (268 MB fp16 gathers + 102 MB weight stream)
// at the ~6.3 TB/s achievable service rate. Keep the best-measured one.
// ---------------------------------------------------------------------------
__global__ __launch_bounds__(256) void row_ffn_kernel(
    const _Float16* __restrict__ in_h,    // [8192, 512] fp16
    const float*    __restrict__ weight,  // [n_rows, 512] fp32
    const float*    __restrict__ bias,    // [n_rows]
    const int*      __restrict__ counts,  // [n_rows]
    const int*      __restrict__ padded,  // [n_rows, 32]
    float*          __restrict__ out,     // [8192, 32]
    int n_rows, int blocks_per_xcd)
{
    const int b    = (int)blockIdx.x;
    const int bsw  = (b & 7) * blocks_per_xcd + (b >> 3);  // XCD-contiguous
    const int wave = threadIdx.x >> 6;
    const int lane = threadIdx.x & 63;
    const int s    = lane & 15;   // sublane within quarter
    const int q    = lane >> 4;   // quarter = which user of the group
    const int r    = bsw * 4 + wave;
    if (r >= n_rows) return;

    const int* users = padded + ((size_t)r << 5);

    // --- front-loaded, mutually independent issues ---
    const int   c_raw = counts[r];
    int         pid_cur = users[q];        // group 0; slots 0..3 always init'd
    const float bv    = bias[r];

    const float* wbase = weight + (size_t)r * HIDDEN + s * 8;
    f32x4 w[8];
#pragma unroll
    for (int j = 0; j < 4; ++j) {
        w[2*j]   = __builtin_nontemporal_load((const f32x4*)(wbase + j*128));
        w[2*j+1] = __builtin_nontemporal_load((const f32x4*)(wbase + j*128 + 4));
    }

    // group-0 gathers, issued before c is even inspected
    const _Float16* irow0 = in_h + (size_t)(pid_cur >> 5) * HIDDEN + s * 8;
    half8 h0 = *(const half8*)(irow0);
    half8 h1 = *(const half8*)(irow0 + 128);
    half8 h2 = *(const half8*)(irow0 + 256);
    half8 h3 = *(const half8*)(irow0 + 384);

    const int c = (c_raw > BUCKET_CAP) ? BUCKET_CAP : c_raw;

    // pipeline stage: group-1 pid + DATA prefetch; group-2 pid prefetch
    int pid_next = 0, pid_next2 = 0;
    half8 n0 = h0, n1 = h1, n2 = h2, n3 = h3;
    if (c > 4) {
        const int g4  = c - 4;
        const int off = (q < g4) ? q : (g4 - 1);
        pid_next = users[4 + off];
        const _Float16* irn = in_h + (size_t)(pid_next >> 5) * HIDDEN + s * 8;
        n0 = *(const half8*)(irn);
        n1 = *(const half8*)(irn + 128);
        n2 = *(const half8*)(irn + 256);
        n3 = *(const half8*)(irn + 384);
    }
    if (c > 8) {
        const int g8  = c - 8;
        const int off = (q < g8) ? q : (g8 - 1);
        pid_next2 = users[8 + off];
    }

    // compute group 0
    float d = dot128(h0, w[0], w[1]) + dot128(h1, w[2], w[3])
            + dot128(h2, w[4], w[5]) + dot128(h3, w[6], w[7]);
    d = red16(d);
    if (s == 0 && q < c) {
        float v = d + bv;
        out[pid_cur] = v > 0.0f ? v : 0.0f;
    }

    for (int u = 4; u < c; u += 4) {
        const int g = c - u;                   // users left this group (>=1)
        pid_cur = pid_next;
        const half8 c0 = n0, c1 = n1, c2 = n2, c3 = n3;

        if (u + 4 < c) {                       // prefetch group u+4 DATA
            pid_next = pid_next2;
            const _Float16* irn =
                in_h + (size_t)(pid_next >> 5) * HIDDEN + s * 8;
            n0 = *(const half8*)(irn);
            n1 = *(const half8*)(irn + 128);
            n2 = *(const half8*)(irn + 256);
            n3 = *(const half8*)(irn + 384);
            if (u + 8 < c) {                   // prefetch group u+8 pid
                const int gn  = c - (u + 8);
                const int off = (q < gn) ? q : (gn - 1);
                pid_next2 = users[u + 8 + off];
            }
        }

        float e = dot128(c0, w[0], w[1]) + dot128(c1, w[2], w[3])
                + dot128(c2, w[4], w[5]) + dot128(c3, w[6], w[7]);
        e = red16(e);
        if (s == 0 && q < g) {
            float v = e + bv;
            out[pid_cur] = v > 0.0f ? v : 0.0f;
        }
    }
}

// ---------------------------------------------------------------------------
// Fallback (ws too small): round-1 fp32 token-centric, known-good 97us.
// ---------------------------------------------------------------------------
__global__ __launch_bounds__(256) void dynamic_ffn_f32_kernel(
    const float* __restrict__ input,
    const int*   __restrict__ mask,
    const float* __restrict__ weight,
    const float* __restrict__ bias,
    float*       __restrict__ out,
    int n_tokens)
{
    const int token = blockIdx.x;
    if (token >= n_tokens) return;
    const int wave = threadIdx.x >> 6;
    const int lane = threadIdx.x & 63;

    const float* in_row = input + (size_t)token * HIDDEN + lane * 8;
    const float4 x0 = *(const float4*)(in_row);
    const float4 x1 = *(const float4*)(in_row + 4);

    const int* midx = mask + (size_t)token * M_PER_TOKEN + wave * 8;
    float*     orow = out  + (size_t)token * M_PER_TOKEN + wave * 8;

    int idx[8];
#pragma unroll
    for (int j = 0; j < 8; ++j) idx[j] = midx[j];

    float acc[8];
#pragma unroll
    for (int j = 0; j < 8; ++j) {
        const float* w = weight + (size_t)idx[j] * HIDDEN + lane * 8;
        const float4 a = *(const float4*)(w);
        const float4 b = *(const float4*)(w + 4);
        acc[j] = x0.x * a.x + x0.y * a.y + x0.z * a.z + x0.w * a.w
               + x1.x * b.x + x1.y * b.y + x1.z * b.z + x1.w * b.w;
    }
#pragma unroll
    for (int j = 0; j < 8; ++j) {
        float p = acc[j];
#pragma unroll
        for (int off = 32; off > 0; off >>= 1)
            p += __shfl_down(p, off, 64);
        if (lane == 0) {
            float v = p + bias[idx[j]];
            orow[j] = v > 0.0f ? v : 0.0f;
        }
    }
}

extern "C" void kernel_launch(void* const* d_in, const int* in_sizes, int n_in,
                              void* d_out, int out_size, void* d_ws, size_t ws_size,
                              hipStream_t stream) {
    const float* input  = (const float*)d_in[0];   // [4,2048,512] fp32
    const int*   mask   = (const int*)  d_in[1];   // [4,2048,32] int32
    const float* weight = (const float*)d_in[2];   // [50000,512] fp32
    const float* bias   = (const float*)d_in[3];   // [50000] fp32
    float*       out    = (float*)d_out;           // [4,2048,32] fp32

    const int n_tokens = in_sizes[0] / HIDDEN;     // 8192
    const int n_pairs  = in_sizes[1];              // 262144
    const int n_rows   = in_sizes[2] / HIDDEN;     // 50000

    const size_t in_h_bytes   = (size_t)in_sizes[0] * sizeof(_Float16);    // 8.4MB
    const size_t counts_bytes = (size_t)n_rows * sizeof(int);              // 200KB
    const size_t padded_bytes = (size_t)n_rows * BUCKET_CAP * sizeof(int); // 6.4MB
    const size_t need = in_h_bytes + counts_bytes + padded_bytes;

    if (ws_size >= need) {
        _Float16* in_h   = (_Float16*)d_ws;
        int*      counts = (int*)((char*)d_ws + in_h_bytes);
        int*      padded = (int*)((char*)d_ws + in_h_bytes + counts_bytes);

        const int n_chunks = in_sizes[0] / 8;      // 524288
        prep_kernel<<<(n_chunks + 255) / 256, 256, 0, stream>>>(
            input, in_h, counts, padded, n_chunks, n_rows);

        const int sc_threads = (n_pairs + 3) / 4;  // 65536
        scatter_kernel<<<(sc_threads + 255) / 256, 256, 0, stream>>>(
            mask, counts, padded, n_pairs);

        const int n_wave_rows    = (n_rows + 3) / 4;         // 12500
        const int blocks_per_xcd = (n_wave_rows + 7) / 8;    // 1563
        const int grid           = blocks_per_xcd * 8;       // 12504
        row_ffn_kernel<<<grid, 256, 0, stream>>>(
            in_h, weight, bias, counts, padded, out, n_rows, blocks_per_xcd);
    } else {
        dynamic_ffn_f32_kernel<<<n_tokens, 256, 0, stream>>>(
            input, mask, weight, bias, out, n_tokens);
    }
}